// Round 1
// baseline (1602.775 us; speedup 1.0000x reference)
//
#include <hip/hip_runtime.h>
#include <hip/hip_bf16.h>
#include <stdint.h>

#define NTOK   131072
#define DM     1024
#define NE     64
#define TB     256        // tokens per block
#define NBLK   512        // NTOK / TB
#define BK     16         // K chunk
#define NCHUNK 64         // DM / BK
#define CAP    2458       // ceil(1.2 * 131072 / 64)

// ---------------------------------------------------------------------------
// Kernel 1: gate projection + noise + softmax + top1 + per-block histograms,
//           within-block stable ranks, per-block softmax column partials.
// One thread = one token. 256 threads/block = 256 consecutive tokens.
// W rows are wave-uniform -> scalar (SGPR) loads; A staged in LDS (dbuf).
// ---------------------------------------------------------------------------
__global__ __launch_bounds__(256, 4)
void gate_kernel(const float* __restrict__ A, const float* __restrict__ W,
                 const float* __restrict__ bias, const float* __restrict__ noise,
                 float* __restrict__ out, int* __restrict__ top1g,
                 int* __restrict__ rankg, int* __restrict__ histg,
                 float* __restrict__ colpart)
{
    __shared__ float asA[2][TB][BK + 1];   // pad 17 -> conflict-free column reads
    __shared__ float wcol[4][NE];
    __shared__ int   whist[4][NE];

    const int tid  = threadIdx.x;
    const int blk  = blockIdx.x;
    const int lane = tid & 63;
    const int wave = tid >> 6;
    const int tokBase = blk * TB;

    float acc[NE];
#pragma unroll
    for (int e = 0; e < NE; ++e) acc[e] = 0.f;

    // staging mapping: 4 consecutive lanes cover a contiguous 64B row-segment
    const int st_t = tid >> 2;         // 0..63
    const int st_k = (tid & 3) << 2;   // 0,4,8,12
    const float* Abase = A + (size_t)tokBase * DM;

    float4 st[4];
    // prologue: chunk 0 -> buf 0
#pragma unroll
    for (int p = 0; p < 4; ++p)
        st[p] = *(const float4*)(Abase + (size_t)(st_t + p * 64) * DM + st_k);
#pragma unroll
    for (int p = 0; p < 4; ++p) {
        float* d = &asA[0][st_t + p * 64][st_k];
        d[0] = st[p].x; d[1] = st[p].y; d[2] = st[p].z; d[3] = st[p].w;
    }
    __syncthreads();

#pragma unroll 1
    for (int c = 0; c < NCHUNK; ++c) {
        const int cur = c & 1;
        // prefetch next chunk global -> regs (latency hides under FMAs)
        if (c + 1 < NCHUNK) {
            const int k0n = (c + 1) * BK;
#pragma unroll
            for (int p = 0; p < 4; ++p)
                st[p] = *(const float4*)(Abase + (size_t)(st_t + p * 64) * DM + k0n + st_k);
        }
        const int k0 = c * BK;
#pragma unroll
        for (int k = 0; k < BK; ++k) {
            const float x = asA[cur][tid][k];
            const float* wrow = W + (size_t)(k0 + k) * NE;   // wave-uniform -> s_load
#pragma unroll
            for (int e = 0; e < NE; ++e)
                acc[e] = fmaf(x, wrow[e], acc[e]);
        }
        if (c + 1 < NCHUNK) {
#pragma unroll
            for (int p = 0; p < 4; ++p) {
                float* d = &asA[cur ^ 1][st_t + p * 64][st_k];
                d[0] = st[p].x; d[1] = st[p].y; d[2] = st[p].z; d[3] = st[p].w;
            }
        }
        __syncthreads();
    }

    // ---- epilogue: bias + noise, softmax, top1 ----
    const int token = tokBase + tid;
    const float* nrow = noise + (size_t)token * NE;
#pragma unroll
    for (int e4 = 0; e4 < 16; ++e4) {
        const float4 nv = ((const float4*)nrow)[e4];
        acc[e4 * 4 + 0] += bias[e4 * 4 + 0] + nv.x * 0.2f + 0.9f;
        acc[e4 * 4 + 1] += bias[e4 * 4 + 1] + nv.y * 0.2f + 0.9f;
        acc[e4 * 4 + 2] += bias[e4 * 4 + 2] + nv.z * 0.2f + 0.9f;
        acc[e4 * 4 + 3] += bias[e4 * 4 + 3] + nv.w * 0.2f + 0.9f;
    }

    float best = acc[0];
    int   bi   = 0;
#pragma unroll
    for (int e = 1; e < NE; ++e)
        if (acc[e] > best) { best = acc[e]; bi = e; }   // strict > keeps first tie (jnp.argmax)

    float denom = 0.f;
#pragma unroll
    for (int e = 0; e < NE; ++e) {
        const float pe = __expf(acc[e] - best);
        acc[e] = pe;
        denom += pe;
    }
    const float inv = 1.0f / denom;
    out[NTOK + token] = inv;           // top1 prob: exp(0)/denom
#pragma unroll
    for (int e = 0; e < NE; ++e) acc[e] *= inv;

    // ---- in-register transpose-reduce: lane l ends with wave-sum of prob[l]
    // all indices compile-time (rule #20), 63 shfl total
#pragma unroll
    for (int m = 32; m; m >>= 1) {
        const bool up = (lane & m) != 0;
#pragma unroll
        for (int j = 0; j < m; ++j) {
            const float send = up ? acc[j] : acc[j + m];
            const float r    = __shfl_xor(send, m, 64);
            const float mine = up ? acc[j + m] : acc[j];
            acc[j] = mine + r;
        }
    }
    wcol[wave][lane] = acc[0];

    // ---- within-block stable rank via per-expert ballot ----
    const uint64_t below = (1ull << lane) - 1ull;
    int lrank = 0;
#pragma unroll 1
    for (int e = 0; e < NE; ++e) {
        const uint64_t mb = __ballot(bi == e);
        if (bi == e)   lrank = __popcll(mb & below);
        if (lane == e) whist[wave][e] = (int)__popcll(mb);
    }
    __syncthreads();

    int rk = lrank;
    for (int w = 0; w < wave; ++w) rk += whist[w][bi];
    top1g[token] = bi;
    rankg[token] = rk;

    if (tid < NE) {
        histg[blk * NE + tid]   = whist[0][tid] + whist[1][tid] + whist[2][tid] + whist[3][tid];
        colpart[blk * NE + tid] = wcol[0][tid] + wcol[1][tid] + wcol[2][tid] + wcol[3][tid];
    }
}

// ---------------------------------------------------------------------------
// Kernel 2: per-expert exclusive scan over 512 block-histograms + loss.
// Single block, 256 threads: thread = (expert, segment-of-128-blocks).
// ---------------------------------------------------------------------------
__global__ void scan_kernel(const int* __restrict__ hist, const float* __restrict__ colpart,
                            int* __restrict__ offsets, float* __restrict__ out)
{
    __shared__ int   segsum[4][NE];
    __shared__ float segcol[4][NE];
    const int tid = threadIdx.x;
    const int e   = tid & 63;
    const int seg = tid >> 6;
    const int b0  = seg * 128, b1 = b0 + 128;

    int s = 0; float cs = 0.f;
    for (int b = b0; b < b1; ++b) { s += hist[b * NE + e]; cs += colpart[b * NE + e]; }
    segsum[seg][e] = s;
    segcol[seg][e] = cs;
    __syncthreads();

    int base = 0;
    for (int w = 0; w < seg; ++w) base += segsum[w][e];
    int run = base;
    for (int b = b0; b < b1; ++b) { offsets[b * NE + e] = run; run += hist[b * NE + e]; }

    if (tid < 64) {
        const int   total = segsum[0][e] + segsum[1][e] + segsum[2][e] + segsum[3][e];
        const float csum  = segcol[0][e] + segcol[1][e] + segcol[2][e] + segcol[3][e];
        const float cnt   = (float)((total < CAP) ? total : CAP);
        float nv = cnt;
        float contrib = cnt * csum;
#pragma unroll
        for (int m = 32; m; m >>= 1) {
            nv      += __shfl_xor(nv, m, 64);
            contrib += __shfl_xor(contrib, m, 64);
        }
        if (tid == 0) out[2 * NTOK] = 64.0f * contrib / (nv * nv);
    }
}

// ---------------------------------------------------------------------------
// Kernel 3: global rank = local rank + block offset; write pruned idx as float.
// ---------------------------------------------------------------------------
__global__ void finalize_kernel(const int* __restrict__ top1g, const int* __restrict__ rankg,
                                const int* __restrict__ offsets, float* __restrict__ out)
{
    const int i = blockIdx.x * 256 + threadIdx.x;
    const int e = top1g[i];
    const int r = rankg[i] + offsets[blockIdx.x * NE + e];
    out[i] = (r < CAP) ? (float)e : -1.0f;
}

extern "C" void kernel_launch(void* const* d_in, const int* in_sizes, int n_in,
                              void* d_out, int out_size, void* d_ws, size_t ws_size,
                              hipStream_t stream)
{
    (void)in_sizes; (void)n_in; (void)out_size; (void)ws_size;
    const float* A     = (const float*)d_in[0];
    const float* W     = (const float*)d_in[1];
    const float* bias  = (const float*)d_in[2];
    const float* noise = (const float*)d_in[3];
    float* out = (float*)d_out;

    char* ws = (char*)d_ws;
    int*   top1g   = (int*)ws;                                   // 512 KB
    int*   rankg   = (int*)(ws + 524288);                        // 512 KB
    int*   histg   = (int*)(ws + 2 * 524288);                    // 128 KB
    int*   offsets = (int*)(ws + 2 * 524288 + 131072);           // 128 KB
    float* colpart = (float*)(ws + 2 * 524288 + 2 * 131072);     // 128 KB

    gate_kernel<<<NBLK, 256, 0, stream>>>(A, W, bias, noise, out, top1g, rankg, histg, colpart);
    scan_kernel<<<1, 256, 0, stream>>>(histg, colpart, offsets, out);
    finalize_kernel<<<NBLK, 256, 0, stream>>>(top1g, rankg, offsets, out);
}

// Round 2
// 1584.622 us; speedup vs baseline: 1.0115x; 1.0115x over previous
//
#include <hip/hip_runtime.h>
#include <hip/hip_bf16.h>
#include <stdint.h>

#define NTOK   131072
#define DM     1024
#define NE     64
#define TB     256        // tokens per block
#define NBLK   512        // NTOK / TB
#define BK     16         // K chunk
#define NCHUNK 64         // DM / BK
#define CAP    2458       // ceil(1.2 * 131072 / 64)

// ---------------------------------------------------------------------------
// Kernel 1: gate projection + noise + softmax + top1 + per-block histograms,
//           within-block stable ranks, per-block softmax column partials.
// One thread = one token. 256 threads/block = 256 consecutive tokens.
// W rows are wave-uniform -> scalar (SGPR) loads; A staged in LDS (dbuf).
// __launch_bounds__(256, 2): VGPR cap 256 so acc[64] stays in registers
// (R1 post-mortem: (256,4) capped at 64 VGPR -> acc spilled, 135 MB scratch
// writes, VALUBusy 34%).
// ---------------------------------------------------------------------------
__global__ __launch_bounds__(256, 2)
void gate_kernel(const float* __restrict__ A, const float* __restrict__ W,
                 const float* __restrict__ bias, const float* __restrict__ noise,
                 float* __restrict__ out, int* __restrict__ top1g,
                 int* __restrict__ rankg, int* __restrict__ histg,
                 float* __restrict__ colpart)
{
    __shared__ float asA[2][TB][BK + 1];   // pad 17 -> 2-way (free) bank aliasing
    __shared__ float wcol[4][NE];
    __shared__ int   whist[4][NE];

    const int tid  = threadIdx.x;
    const int blk  = blockIdx.x;
    const int lane = tid & 63;
    const int wave = tid >> 6;
    const int tokBase = blk * TB;

    float acc[NE];
#pragma unroll
    for (int e = 0; e < NE; ++e) acc[e] = 0.f;

    // staging mapping: 4 consecutive lanes cover a contiguous 64B row-segment
    const int st_t = tid >> 2;         // 0..63
    const int st_k = (tid & 3) << 2;   // 0,4,8,12
    const float* Abase = A + (size_t)tokBase * DM;

    float4 st[4];
    // prologue: chunk 0 -> buf 0
#pragma unroll
    for (int p = 0; p < 4; ++p)
        st[p] = *(const float4*)(Abase + (size_t)(st_t + p * 64) * DM + st_k);
#pragma unroll
    for (int p = 0; p < 4; ++p) {
        float* d = &asA[0][st_t + p * 64][st_k];
        d[0] = st[p].x; d[1] = st[p].y; d[2] = st[p].z; d[3] = st[p].w;
    }
    __syncthreads();

#pragma unroll 1
    for (int c = 0; c < NCHUNK; ++c) {
        const int cur = c & 1;
        // prefetch next chunk global -> regs (latency hides under FMAs)
        if (c + 1 < NCHUNK) {
            const int k0n = (c + 1) * BK;
#pragma unroll
            for (int p = 0; p < 4; ++p)
                st[p] = *(const float4*)(Abase + (size_t)(st_t + p * 64) * DM + k0n + st_k);
        }
        const int k0 = c * BK;
#pragma unroll
        for (int k = 0; k < BK; ++k) {
            const float x = asA[cur][tid][k];
            const float* wrow = W + (size_t)(k0 + k) * NE;   // wave-uniform -> s_load
#pragma unroll
            for (int e = 0; e < NE; ++e)
                acc[e] = fmaf(x, wrow[e], acc[e]);
        }
        if (c + 1 < NCHUNK) {
#pragma unroll
            for (int p = 0; p < 4; ++p) {
                float* d = &asA[cur ^ 1][st_t + p * 64][st_k];
                d[0] = st[p].x; d[1] = st[p].y; d[2] = st[p].z; d[3] = st[p].w;
            }
        }
        __syncthreads();
    }

    // ---- epilogue: bias + noise, softmax, top1 ----
    const int token = tokBase + tid;
    const float* nrow = noise + (size_t)token * NE;
#pragma unroll
    for (int e4 = 0; e4 < 16; ++e4) {
        const float4 nv = ((const float4*)nrow)[e4];
        acc[e4 * 4 + 0] += bias[e4 * 4 + 0] + nv.x * 0.2f + 0.9f;
        acc[e4 * 4 + 1] += bias[e4 * 4 + 1] + nv.y * 0.2f + 0.9f;
        acc[e4 * 4 + 2] += bias[e4 * 4 + 2] + nv.z * 0.2f + 0.9f;
        acc[e4 * 4 + 3] += bias[e4 * 4 + 3] + nv.w * 0.2f + 0.9f;
    }

    float best = acc[0];
    int   bi   = 0;
#pragma unroll
    for (int e = 1; e < NE; ++e)
        if (acc[e] > best) { best = acc[e]; bi = e; }   // strict > keeps first tie (jnp.argmax)

    float denom = 0.f;
#pragma unroll
    for (int e = 0; e < NE; ++e) {
        const float pe = __expf(acc[e] - best);
        acc[e] = pe;
        denom += pe;
    }
    const float inv = 1.0f / denom;
    out[NTOK + token] = inv;           // top1 prob: exp(0)/denom
#pragma unroll
    for (int e = 0; e < NE; ++e) acc[e] *= inv;

    // ---- in-register transpose-reduce: lane l ends with wave-sum of prob[l]
    // all indices compile-time (rule #20), 63 shfl total
#pragma unroll
    for (int m = 32; m; m >>= 1) {
        const bool up = (lane & m) != 0;
#pragma unroll
        for (int j = 0; j < m; ++j) {
            const float send = up ? acc[j] : acc[j + m];
            const float r    = __shfl_xor(send, m, 64);
            const float mine = up ? acc[j + m] : acc[j];
            acc[j] = mine + r;
        }
    }
    wcol[wave][lane] = acc[0];

    // ---- within-block stable rank via per-expert ballot ----
    const uint64_t below = (1ull << lane) - 1ull;
    int lrank = 0;
#pragma unroll 1
    for (int e = 0; e < NE; ++e) {
        const uint64_t mb = __ballot(bi == e);
        if (bi == e)   lrank = __popcll(mb & below);
        if (lane == e) whist[wave][e] = (int)__popcll(mb);
    }
    __syncthreads();

    int rk = lrank;
    for (int w = 0; w < wave; ++w) rk += whist[w][bi];
    top1g[token] = bi;
    rankg[token] = rk;

    if (tid < NE) {
        histg[blk * NE + tid]   = whist[0][tid] + whist[1][tid] + whist[2][tid] + whist[3][tid];
        colpart[blk * NE + tid] = wcol[0][tid] + wcol[1][tid] + wcol[2][tid] + wcol[3][tid];
    }
}

// ---------------------------------------------------------------------------
// Kernel 2: per-expert exclusive scan over 512 block-histograms + loss.
// Single block, 256 threads: thread = (expert, segment-of-128-blocks).
// ---------------------------------------------------------------------------
__global__ void scan_kernel(const int* __restrict__ hist, const float* __restrict__ colpart,
                            int* __restrict__ offsets, float* __restrict__ out)
{
    __shared__ int   segsum[4][NE];
    __shared__ float segcol[4][NE];
    const int tid = threadIdx.x;
    const int e   = tid & 63;
    const int seg = tid >> 6;
    const int b0  = seg * 128, b1 = b0 + 128;

    int s = 0; float cs = 0.f;
    for (int b = b0; b < b1; ++b) { s += hist[b * NE + e]; cs += colpart[b * NE + e]; }
    segsum[seg][e] = s;
    segcol[seg][e] = cs;
    __syncthreads();

    int base = 0;
    for (int w = 0; w < seg; ++w) base += segsum[w][e];
    int run = base;
    for (int b = b0; b < b1; ++b) { offsets[b * NE + e] = run; run += hist[b * NE + e]; }

    if (tid < 64) {
        const int   total = segsum[0][e] + segsum[1][e] + segsum[2][e] + segsum[3][e];
        const float csum  = segcol[0][e] + segcol[1][e] + segcol[2][e] + segcol[3][e];
        const float cnt   = (float)((total < CAP) ? total : CAP);
        float nv = cnt;
        float contrib = cnt * csum;
#pragma unroll
        for (int m = 32; m; m >>= 1) {
            nv      += __shfl_xor(nv, m, 64);
            contrib += __shfl_xor(contrib, m, 64);
        }
        if (tid == 0) out[2 * NTOK] = 64.0f * contrib / (nv * nv);
    }
}

// ---------------------------------------------------------------------------
// Kernel 3: global rank = local rank + block offset; write pruned idx as float.
// ---------------------------------------------------------------------------
__global__ void finalize_kernel(const int* __restrict__ top1g, const int* __restrict__ rankg,
                                const int* __restrict__ offsets, float* __restrict__ out)
{
    const int i = blockIdx.x * 256 + threadIdx.x;
    const int e = top1g[i];
    const int r = rankg[i] + offsets[blockIdx.x * NE + e];
    out[i] = (r < CAP) ? (float)e : -1.0f;
}

extern "C" void kernel_launch(void* const* d_in, const int* in_sizes, int n_in,
                              void* d_out, int out_size, void* d_ws, size_t ws_size,
                              hipStream_t stream)
{
    (void)in_sizes; (void)n_in; (void)out_size; (void)ws_size;
    const float* A     = (const float*)d_in[0];
    const float* W     = (const float*)d_in[1];
    const float* bias  = (const float*)d_in[2];
    const float* noise = (const float*)d_in[3];
    float* out = (float*)d_out;

    char* ws = (char*)d_ws;
    int*   top1g   = (int*)ws;                                   // 512 KB
    int*   rankg   = (int*)(ws + 524288);                        // 512 KB
    int*   histg   = (int*)(ws + 2 * 524288);                    // 128 KB
    int*   offsets = (int*)(ws + 2 * 524288 + 131072);           // 128 KB
    float* colpart = (float*)(ws + 2 * 524288 + 2 * 131072);     // 128 KB

    gate_kernel<<<NBLK, 256, 0, stream>>>(A, W, bias, noise, out, top1g, rankg, histg, colpart);
    scan_kernel<<<1, 256, 0, stream>>>(histg, colpart, offsets, out);
    finalize_kernel<<<NBLK, 256, 0, stream>>>(top1g, rankg, offsets, out);
}

// Round 3
// 637.248 us; speedup vs baseline: 2.5152x; 2.4867x over previous
//
#include <hip/hip_runtime.h>
#include <stdint.h>

#define NTOK   131072
#define DM     1024
#define NE     64
#define TB     64         // tokens per block
#define NBLK   2048       // NTOK / TB
#define BK     16         // K chunk
#define NCHUNK 64         // DM / BK
#define CAP    2458       // ceil(1.2 * 131072 / 64)
#define EPG    16         // experts per group (per wave)

// ---------------------------------------------------------------------------
// gate_kernel: 256 threads = 4 waves = 64 tokens x 4 expert-groups.
// thread (g, lane): token = blk*64+lane, experts [g*16, g*16+16).
// Rationale (R2 post-mortem): thread=token gave only 2048 waves total
// (2 waves/SIMD, VALUBusy 34%) and acc[64] made the allocator spill the
// epilogue (133 MB scratch writes). 4x thread split -> 8 waves/SIMD
// potential and acc[16] -> no spill at any occupancy target.
// ---------------------------------------------------------------------------
__global__ __launch_bounds__(256, 4)
void gate_kernel(const float* __restrict__ A, const float* __restrict__ W,
                 const float* __restrict__ bias, const float* __restrict__ noise,
                 float* __restrict__ out, int* __restrict__ pk,
                 int* __restrict__ histg, float* __restrict__ colpart)
{
    __shared__ float asA[2][TB][BK + 1];   // pad 17 -> 2-way (free) bank aliasing
    __shared__ float smax[TB][5];          // pad 5 -> 2-way
    __shared__ float ssum[TB][5];
    __shared__ int   sidx[TB][5];

    const int tid  = threadIdx.x;
    const int lane = tid & 63;                                   // token-in-block
    const int g16  = __builtin_amdgcn_readfirstlane((tid >> 6) << 4); // SGPR expert base
    const int blk  = blockIdx.x;
    const int tokBase = blk * TB;
    const int token   = tokBase + lane;

    float acc[EPG];
#pragma unroll
    for (int e = 0; e < EPG; ++e) acc[e] = 0.f;

    // staging: thread loads ONE float4; 4 consecutive threads cover one row-chunk
    const int st_t = tid >> 2;          // 0..63 token row
    const int st_k = (tid & 3) << 2;    // 0,4,8,12
    const float* Abase = A + (size_t)tokBase * DM;

    float4 st = *(const float4*)(Abase + (size_t)st_t * DM + st_k);
    { float* d = &asA[0][st_t][st_k]; d[0] = st.x; d[1] = st.y; d[2] = st.z; d[3] = st.w; }
    __syncthreads();

#pragma unroll 1
    for (int c = 0; c < NCHUNK; ++c) {
        const int cur = c & 1;
        if (c + 1 < NCHUNK)  // prefetch next chunk; vmcnt hides under 256 FMAs
            st = *(const float4*)(Abase + (size_t)st_t * DM + (c + 1) * BK + st_k);
        const int k0 = c * BK;
#pragma unroll
        for (int kq = 0; kq < 4; ++kq) {
            const float4 xq = *(const float4*)&asA[cur][lane][kq * 4];
            const float xs[4] = {xq.x, xq.y, xq.z, xq.w};
#pragma unroll
            for (int kk = 0; kk < 4; ++kk) {
                const float x = xs[kk];
                const float* wrow = W + (size_t)(k0 + kq * 4 + kk) * NE + g16; // uniform -> s_load
#pragma unroll
                for (int e = 0; e < EPG; ++e)
                    acc[e] = fmaf(x, wrow[e], acc[e]);
            }
        }
        if (c + 1 < NCHUNK) {
            float* d = &asA[cur ^ 1][st_t][st_k];
            d[0] = st.x; d[1] = st.y; d[2] = st.z; d[3] = st.w;
        }
        __syncthreads();   // one barrier per chunk: dbuf write->read and WAR both covered
    }

    // ---- bias + noise ----
    const float* nrow = noise + (size_t)token * NE + g16;
    const float* brow = bias + g16;                    // uniform -> s_load
#pragma unroll
    for (int q = 0; q < 4; ++q) {
        const float4 nv = ((const float4*)nrow)[q];
        acc[q * 4 + 0] += brow[q * 4 + 0] + nv.x * 0.2f + 0.9f;
        acc[q * 4 + 1] += brow[q * 4 + 1] + nv.y * 0.2f + 0.9f;
        acc[q * 4 + 2] += brow[q * 4 + 2] + nv.z * 0.2f + 0.9f;
        acc[q * 4 + 3] += brow[q * 4 + 3] + nv.w * 0.2f + 0.9f;
    }

    // ---- local (group) max/argmax, then combine 4 groups via LDS ----
    float lm = acc[0]; int li = 0;
#pragma unroll
    for (int e = 1; e < EPG; ++e)
        if (acc[e] > lm) { lm = acc[e]; li = e; }   // strict > : first tie wins
    const int g = g16 >> 4;
    smax[lane][g] = lm;
    sidx[lane][g] = g16 + li;
    __syncthreads();

    float M = smax[lane][0]; int bi = sidx[lane][0];
#pragma unroll
    for (int g2 = 1; g2 < 4; ++g2) {
        const float m2 = smax[lane][g2];
        if (m2 > M) { M = m2; bi = sidx[lane][g2]; }  // ascending g2 + strict > = lowest idx on tie
    }

    float s = 0.f;
#pragma unroll
    for (int e = 0; e < EPG; ++e) { acc[e] = __expf(acc[e] - M); s += acc[e]; }
    ssum[lane][g] = s;
    __syncthreads();
    const float denom = ssum[lane][0] + ssum[lane][1] + ssum[lane][2] + ssum[lane][3];
    const float inv = 1.0f / denom;
#pragma unroll
    for (int e = 0; e < EPG; ++e) acc[e] *= inv;

    if (g16 == 0) out[NTOK + token] = inv;   // top1 prob = exp(0)/denom

    // ---- per-wave column sums: constant-bound butterfly (rule #20 safe) ----
#define XSTAGE(M_)                                                       \
    {                                                                    \
        const bool up_ = (lane & (M_)) != 0;                             \
        _Pragma("unroll")                                                \
        for (int j = 0; j < (M_); ++j) {                                 \
            const float a_ = acc[j], b_ = acc[j + (M_)];                 \
            const float r_ = __shfl_xor(up_ ? a_ : b_, (M_), 64);        \
            acc[j] = (up_ ? b_ : a_) + r_;                               \
        }                                                                \
    }
    XSTAGE(8) XSTAGE(4) XSTAGE(2) XSTAGE(1)
#undef XSTAGE
    float cs = acc[0];
    cs += __shfl_xor(cs, 16, 64);
    cs += __shfl_xor(cs, 32, 64);
    if (lane < EPG) colpart[blk * NE + g16 + lane] = cs;  // expert g16+lane column sum

    // ---- stable within-block rank + histogram: wave 0 only (lane == token) ----
    if (g16 == 0) {
        const uint64_t below = (1ull << lane) - 1ull;
        int lrank = 0, h = 0;
#pragma unroll 1
        for (int e = 0; e < NE; ++e) {
            const uint64_t mb = __ballot(bi == e);
            if (bi == e)   lrank = (int)__popcll(mb & below);
            if (lane == e) h = (int)__popcll(mb);
        }
        pk[token] = bi | (lrank << 6);      // pack: 6b expert + local rank
        histg[blk * NE + lane] = h;
    }
}

// ---------------------------------------------------------------------------
// scan_kernel: per-expert exclusive scan over 2048 block histograms (in-place:
// hist -> offsets) + load-balancing loss. 1 block, 256 threads = 64 experts x
// 4 segments of 512 blocks.
// ---------------------------------------------------------------------------
__global__ void scan_kernel(int* __restrict__ hist, const float* __restrict__ colpart,
                            float* __restrict__ out)
{
    __shared__ int   segsum[4][NE];
    __shared__ float segcol[4][NE];
    const int tid = threadIdx.x;
    const int e   = tid & 63;
    const int seg = tid >> 6;
    const int b0  = seg * 512, b1 = b0 + 512;

    int s = 0; float cs = 0.f;
    for (int b = b0; b < b1; ++b) { s += hist[b * NE + e]; cs += colpart[b * NE + e]; }
    segsum[seg][e] = s;
    segcol[seg][e] = cs;
    __syncthreads();

    int run = 0;
    for (int w = 0; w < seg; ++w) run += segsum[w][e];
    for (int b = b0; b < b1; ++b) {         // in-place: read h, write prefix
        const int h = hist[b * NE + e];
        hist[b * NE + e] = run;
        run += h;
    }

    if (tid < 64) {
        const int   total = segsum[0][e] + segsum[1][e] + segsum[2][e] + segsum[3][e];
        const float csum  = segcol[0][e] + segcol[1][e] + segcol[2][e] + segcol[3][e];
        const float cnt   = (float)((total < CAP) ? total : CAP);
        float nv = cnt;
        float contrib = cnt * csum;
#pragma unroll
        for (int m = 32; m; m >>= 1) {
            nv      += __shfl_xor(nv, m, 64);
            contrib += __shfl_xor(contrib, m, 64);
        }
        if (tid == 0) out[2 * NTOK] = 64.0f * contrib / (nv * nv);
    }
}

// ---------------------------------------------------------------------------
// finalize: global rank = local rank + block offset; write pruned idx as float.
// ---------------------------------------------------------------------------
__global__ void finalize_kernel(const int* __restrict__ pk, const int* __restrict__ offs,
                                float* __restrict__ out)
{
    const int i = blockIdx.x * 256 + threadIdx.x;
    const int v = pk[i];
    const int e = v & 63;
    const int r = (v >> 6) + offs[(i >> 6) * NE + e];
    out[i] = (r < CAP) ? (float)e : -1.0f;
}

extern "C" void kernel_launch(void* const* d_in, const int* in_sizes, int n_in,
                              void* d_out, int out_size, void* d_ws, size_t ws_size,
                              hipStream_t stream)
{
    (void)in_sizes; (void)n_in; (void)out_size; (void)ws_size;
    const float* A     = (const float*)d_in[0];
    const float* W     = (const float*)d_in[1];
    const float* bias  = (const float*)d_in[2];
    const float* noise = (const float*)d_in[3];
    float* out = (float*)d_out;

    char* ws = (char*)d_ws;
    int*   pkbuf   = (int*)ws;                       // 512 KB
    int*   histg   = (int*)(ws + 524288);            // 512 KB (becomes offsets in-place)
    float* colpart = (float*)(ws + 2 * 524288);      // 512 KB

    gate_kernel<<<NBLK, 256, 0, stream>>>(A, W, bias, noise, out, pkbuf, histg, colpart);
    scan_kernel<<<1, 256, 0, stream>>>(histg, colpart, out);
    finalize_kernel<<<NTOK / 256, 256, 0, stream>>>(pkbuf, histg, out);
}

// Round 4
// 265.817 us; speedup vs baseline: 6.0296x; 2.3973x over previous
//
#include <hip/hip_runtime.h>
#include <stdint.h>

#define NTOK   131072
#define DM     1024
#define NE     64
#define TB     64         // tokens per block
#define NBLK   2048       // NTOK / TB
#define BK     32         // K chunk
#define NCHUNK 32         // DM / BK
#define CAP    2458       // ceil(1.2 * 131072 / 64)
#define EPG    16         // experts per group (per wave)

// global -> LDS direct (16B per lane, wave-uniform LDS base + lane*16)
__device__ __forceinline__ void gload_lds16(const float* g, float* l) {
    __builtin_amdgcn_global_load_lds(
        (const __attribute__((address_space(1))) void*)g,
        (__attribute__((address_space(3))) void*)l, 16, 0, 0);
}

// ---------------------------------------------------------------------------
// gate_kernel: 256 threads = 4 waves = 64 tokens x 4 expert-groups.
// thread (wv, lane): token = blk*64+lane, experts [wv*16, wv*16+16).
// R3 post-mortem: waves were ~97% stalled — mid-chunk vmcnt drain (reg->LDS
// staging), 64 barrier full-drains, and s_load/ds_read lgkmcnt mixing.
// R4: A staged via global_load_lds (no staging regs, no ds_write, load
// drains only at the end-of-chunk barrier with 512 FMAs of slack), BK=32
// (32 barriers), XOR-swizzled tile (linear dest required by global_load_lds;
// swizzle on the global SOURCE address + same XOR on ds_read — rule #21).
// ---------------------------------------------------------------------------
__global__ __launch_bounds__(256, 8)
void gate_kernel(const float* __restrict__ A, const float* __restrict__ W,
                 const float* __restrict__ bias, const float* __restrict__ noise,
                 float* __restrict__ out, int* __restrict__ pk,
                 int* __restrict__ histg, float* __restrict__ colpart)
{
    __shared__ float asA[2][TB][BK];   // LINEAR (global_load_lds) + XOR swizzle
    __shared__ float smax[TB][5];      // pad 5 -> <=2-way (free)
    __shared__ float ssum[TB][5];
    __shared__ int   sidx[TB][5];

    const int tid  = threadIdx.x;
    const int lane = tid & 63;                                 // token-in-block
    const int wv   = __builtin_amdgcn_readfirstlane(tid >> 6); // wave id (SGPR)
    const int g16  = wv << 4;                                  // expert base
    const int blk  = blockIdx.x;
    const int tokBase = blk * TB;
    const int token   = tokBase + lane;

    float acc[EPG];
#pragma unroll
    for (int e = 0; e < EPG; ++e) acc[e] = 0.f;

    // Swizzle: row t stores logical 16B-slot s at physical slot s^(t&7).
    // global_load_lds writes lane -> uniform_base + lane*16 (linear), so each
    // lane fetches the global data belonging at its physical slot:
    //   lane covers row t = wv*16 + j*8 + (lane>>3), physical slot p = lane&7,
    //   logical slot sl = p ^ (t&7) = (lane&7) ^ ((lane>>3)&7).
    const int sl = (lane & 7) ^ ((lane >> 3) & 7);
    const float* gsrc = A + (size_t)(tokBase + wv * 16 + (lane >> 3)) * DM + sl * 4;
    float* lb[2] = { &asA[0][wv * 16][0], &asA[1][wv * 16][0] };

    // prologue: stage chunk 0 into buf 0 (2 calls/wave = 16 rows)
    gload_lds16(gsrc,          lb[0]);
    gload_lds16(gsrc + 8 * DM, lb[0] + 8 * BK);
    __syncthreads();   // compiler-emitted vmcnt(0) drain covers the stage

#pragma unroll 1
    for (int c = 0; c < NCHUNK; ++c) {
        const int cur = c & 1;
        if (c + 1 < NCHUNK) {   // issue next-chunk stage BEFORE compute (2-phase)
            const float* gn = gsrc + (size_t)(c + 1) * BK;
            float* ln = lb[cur ^ 1];
            gload_lds16(gn,          ln);
            gload_lds16(gn + 8 * DM, ln + 8 * BK);
        }
        const float* arow = &asA[cur][lane][0];
        const int k0 = c * BK;
#pragma unroll
        for (int q = 0; q < 8; ++q) {
            const float4 xq = *(const float4*)(arow + ((q ^ (lane & 7)) << 2));
            const float xs[4] = {xq.x, xq.y, xq.z, xq.w};
#pragma unroll
            for (int kk = 0; kk < 4; ++kk) {
                const float x = xs[kk];
                const float* wrow = W + (size_t)(k0 + q * 4 + kk) * NE + g16; // uniform -> s_load
#pragma unroll
                for (int e = 0; e < EPG; ++e)
                    acc[e] = fmaf(x, wrow[e], acc[e]);
            }
        }
        __syncthreads();   // single drain point per chunk (vmcnt for stage + WAR)
    }

    // ---- bias + noise ----
    const float* nrow = noise + (size_t)token * NE + g16;
    const float* brow = bias + g16;                    // uniform -> s_load
#pragma unroll
    for (int q = 0; q < 4; ++q) {
        const float4 nv = ((const float4*)nrow)[q];
        acc[q * 4 + 0] += brow[q * 4 + 0] + nv.x * 0.2f + 0.9f;
        acc[q * 4 + 1] += brow[q * 4 + 1] + nv.y * 0.2f + 0.9f;
        acc[q * 4 + 2] += brow[q * 4 + 2] + nv.z * 0.2f + 0.9f;
        acc[q * 4 + 3] += brow[q * 4 + 3] + nv.w * 0.2f + 0.9f;
    }

    // ---- local (group) max/argmax, then combine 4 groups via LDS ----
    float lm = acc[0]; int li = 0;
#pragma unroll
    for (int e = 1; e < EPG; ++e)
        if (acc[e] > lm) { lm = acc[e]; li = e; }   // strict > : first tie wins
    smax[lane][wv] = lm;
    sidx[lane][wv] = g16 + li;
    __syncthreads();

    float M = smax[lane][0]; int bi = sidx[lane][0];
#pragma unroll
    for (int g2 = 1; g2 < 4; ++g2) {
        const float m2 = smax[lane][g2];
        if (m2 > M) { M = m2; bi = sidx[lane][g2]; }  // ascending g2 + strict > = lowest idx on tie
    }

    float s = 0.f;
#pragma unroll
    for (int e = 0; e < EPG; ++e) { acc[e] = __expf(acc[e] - M); s += acc[e]; }
    ssum[lane][wv] = s;
    __syncthreads();
    const float denom = ssum[lane][0] + ssum[lane][1] + ssum[lane][2] + ssum[lane][3];
    const float inv = 1.0f / denom;
#pragma unroll
    for (int e = 0; e < EPG; ++e) acc[e] *= inv;

    if (wv == 0) out[NTOK + token] = inv;   // top1 prob = exp(0)/denom

    // ---- per-wave column sums: constant-bound butterfly (rule #20 safe) ----
#define XSTAGE(M_)                                                       \
    {                                                                    \
        const bool up_ = (lane & (M_)) != 0;                             \
        _Pragma("unroll")                                                \
        for (int j = 0; j < (M_); ++j) {                                 \
            const float a_ = acc[j], b_ = acc[j + (M_)];                 \
            const float r_ = __shfl_xor(up_ ? a_ : b_, (M_), 64);        \
            acc[j] = (up_ ? b_ : a_) + r_;                               \
        }                                                                \
    }
    XSTAGE(8) XSTAGE(4) XSTAGE(2) XSTAGE(1)
#undef XSTAGE
    float cs = acc[0];
    cs += __shfl_xor(cs, 16, 64);
    cs += __shfl_xor(cs, 32, 64);
    if (lane < EPG) colpart[blk * NE + g16 + lane] = cs;  // expert g16+lane column sum

    // ---- stable within-block rank + histogram: wave 0 only (lane == token) ----
    if (wv == 0) {
        const uint64_t below = (1ull << lane) - 1ull;
        int lrank = 0, h = 0;
#pragma unroll 1
        for (int e = 0; e < NE; ++e) {
            const uint64_t mb = __ballot(bi == e);
            if (bi == e)   lrank = (int)__popcll(mb & below);
            if (lane == e) h = (int)__popcll(mb);
        }
        pk[token] = bi | (lrank << 6);      // pack: 6b expert + local rank
        histg[blk * NE + lane] = h;
    }
}

// ---------------------------------------------------------------------------
// scan_kernel: per-expert exclusive scan over 2048 block histograms (in-place:
// hist -> offsets) + load-balancing loss. 1 block, 256 threads = 64 experts x
// 4 segments of 512 blocks.
// ---------------------------------------------------------------------------
__global__ void scan_kernel(int* __restrict__ hist, const float* __restrict__ colpart,
                            float* __restrict__ out)
{
    __shared__ int   segsum[4][NE];
    __shared__ float segcol[4][NE];
    const int tid = threadIdx.x;
    const int e   = tid & 63;
    const int seg = tid >> 6;
    const int b0  = seg * 512, b1 = b0 + 512;

    int s = 0; float cs = 0.f;
    for (int b = b0; b < b1; ++b) { s += hist[b * NE + e]; cs += colpart[b * NE + e]; }
    segsum[seg][e] = s;
    segcol[seg][e] = cs;
    __syncthreads();

    int run = 0;
    for (int w = 0; w < seg; ++w) run += segsum[w][e];
    for (int b = b0; b < b1; ++b) {         // in-place: read h, write prefix
        const int h = hist[b * NE + e];
        hist[b * NE + e] = run;
        run += h;
    }

    if (tid < 64) {
        const int   total = segsum[0][e] + segsum[1][e] + segsum[2][e] + segsum[3][e];
        const float csum  = segcol[0][e] + segcol[1][e] + segcol[2][e] + segcol[3][e];
        const float cnt   = (float)((total < CAP) ? total : CAP);
        float nv = cnt;
        float contrib = cnt * csum;
#pragma unroll
        for (int m = 32; m; m >>= 1) {
            nv      += __shfl_xor(nv, m, 64);
            contrib += __shfl_xor(contrib, m, 64);
        }
        if (tid == 0) out[2 * NTOK] = 64.0f * contrib / (nv * nv);
    }
}

// ---------------------------------------------------------------------------
// finalize: global rank = local rank + block offset; write pruned idx as float.
// ---------------------------------------------------------------------------
__global__ void finalize_kernel(const int* __restrict__ pk, const int* __restrict__ offs,
                                float* __restrict__ out)
{
    const int i = blockIdx.x * 256 + threadIdx.x;
    const int v = pk[i];
    const int e = v & 63;
    const int r = (v >> 6) + offs[(i >> 6) * NE + e];
    out[i] = (r < CAP) ? (float)e : -1.0f;
}

extern "C" void kernel_launch(void* const* d_in, const int* in_sizes, int n_in,
                              void* d_out, int out_size, void* d_ws, size_t ws_size,
                              hipStream_t stream)
{
    (void)in_sizes; (void)n_in; (void)out_size; (void)ws_size;
    const float* A     = (const float*)d_in[0];
    const float* W     = (const float*)d_in[1];
    const float* bias  = (const float*)d_in[2];
    const float* noise = (const float*)d_in[3];
    float* out = (float*)d_out;

    char* ws = (char*)d_ws;
    int*   pkbuf   = (int*)ws;                       // 512 KB
    int*   histg   = (int*)(ws + 524288);            // 512 KB (becomes offsets in-place)
    float* colpart = (float*)(ws + 2 * 524288);      // 512 KB

    gate_kernel<<<NBLK, 256, 0, stream>>>(A, W, bias, noise, out, pkbuf, histg, colpart);
    scan_kernel<<<1, 256, 0, stream>>>(histg, colpart, out);
    finalize_kernel<<<NTOK / 256, 256, 0, stream>>>(pkbuf, histg, out);
}

// Round 5
// 252.712 us; speedup vs baseline: 6.3423x; 1.0519x over previous
//
#include <hip/hip_runtime.h>
#include <stdint.h>

#define NTOK   131072
#define DM     1024
#define NE     64
#define TB     64         // tokens per block
#define NBLK   2048       // NTOK / TB
#define BK     32         // K chunk
#define NCHUNK 32         // DM / BK
#define CAP    2458       // ceil(1.2 * 131072 / 64)
#define EPG    16         // experts per group (per wave)

// global -> LDS direct (16B per lane, wave-uniform LDS base + lane*16)
__device__ __forceinline__ void gload_lds16(const float* g, float* l) {
    __builtin_amdgcn_global_load_lds(
        (const __attribute__((address_space(1))) void*)g,
        (__attribute__((address_space(3))) void*)l, 16, 0, 0);
}

// ---------------------------------------------------------------------------
// gate_kernel: 256 threads = 4 waves = 64 tokens x 4 expert-groups.
// R4 post-mortem: __syncthreads() per chunk = structural vmcnt(0)+lgkmcnt(0)
// drain — waits for the just-issued next-chunk gloads (~900cy HBM) and
// convoys the block. R5: T3/T4 2-barrier schedule — raw s_barrier (no drain)
// + counted vmcnt(2) so next-chunk loads stay in flight ACROSS the barrier.
//   B1: WAR fence (all waves done reading buf[(c+1)&1] from compute(c-1))
//   stage(c+1) -> buf[(c+1)&1]
//   vmcnt(2): my chunk-c loads landed (in-order counter), c+1's 2 outstanding
//   B2: all waves' chunk-c rows visible -> compute(c)
// ---------------------------------------------------------------------------
__global__ __launch_bounds__(256, 8)
void gate_kernel(const float* __restrict__ A, const float* __restrict__ W,
                 const float* __restrict__ bias, const float* __restrict__ noise,
                 float* __restrict__ out, int* __restrict__ pk,
                 int* __restrict__ histg, float* __restrict__ colpart)
{
    __shared__ float asA[2][TB][BK];   // LINEAR (global_load_lds) + XOR swizzle
    __shared__ float smax[TB][5];      // pad 5 -> <=2-way (free)
    __shared__ float ssum[TB][5];
    __shared__ int   sidx[TB][5];

    const int tid  = threadIdx.x;
    const int lane = tid & 63;                                 // token-in-block
    const int wv   = __builtin_amdgcn_readfirstlane(tid >> 6); // wave id (SGPR)
    const int g16  = wv << 4;                                  // expert base
    const int blk  = blockIdx.x;
    const int tokBase = blk * TB;
    const int token   = tokBase + lane;

    float acc[EPG];
#pragma unroll
    for (int e = 0; e < EPG; ++e) acc[e] = 0.f;

    // Swizzle (rule #21 both-sides): row t stores logical 16B-slot s at
    // physical slot s^(t&7); realized by pre-swizzling the GLOBAL source
    // (global_load_lds dest must be linear), un-done on the ds_read side.
    const int sl = (lane & 7) ^ ((lane >> 3) & 7);
    const float* gsrc = A + (size_t)(tokBase + wv * 16 + (lane >> 3)) * DM + sl * 4;
    float* lb[2] = { &asA[0][wv * 16][0], &asA[1][wv * 16][0] };

    // prologue: stage chunk 0 into buf 0 (2 calls/wave = 16 rows); 2 outstanding
    gload_lds16(gsrc,          lb[0]);
    gload_lds16(gsrc + 8 * DM, lb[0] + 8 * BK);

#pragma unroll 1
    for (int c = 0; c < NCHUNK; ++c) {
        const int cur = c & 1;
        __builtin_amdgcn_s_barrier();            // B1: WAR fence (no drain)
        asm volatile("" ::: "memory");
        if (c + 1 < NCHUNK) {
            const float* gn = gsrc + (size_t)(c + 1) * BK;
            float* ln = lb[cur ^ 1];
            gload_lds16(gn,          ln);
            gload_lds16(gn + 8 * DM, ln + 8 * BK);
            asm volatile("s_waitcnt vmcnt(2)" ::: "memory");  // chunk c landed
        } else {
            asm volatile("s_waitcnt vmcnt(0)" ::: "memory");  // tail: drain
        }
        __builtin_amdgcn_sched_barrier(0);
        __builtin_amdgcn_s_barrier();            // B2: chunk c visible to all
        asm volatile("" ::: "memory");

        const float* arow = &asA[cur][lane][0];
        const int k0 = c * BK;
#pragma unroll
        for (int q = 0; q < 8; ++q) {
            const float4 xq = *(const float4*)(arow + ((q ^ (lane & 7)) << 2));
            const float xs[4] = {xq.x, xq.y, xq.z, xq.w};
#pragma unroll
            for (int kk = 0; kk < 4; ++kk) {
                const float x = xs[kk];
                const float* wrow = W + (size_t)(k0 + q * 4 + kk) * NE + g16; // uniform -> s_load
#pragma unroll
                for (int e = 0; e < EPG; ++e)
                    acc[e] = fmaf(x, wrow[e], acc[e]);
            }
        }
    }
    __syncthreads();   // epilogue boundary (full drain once)

    // ---- bias + noise ----
    const float* nrow = noise + (size_t)token * NE + g16;
    const float* brow = bias + g16;                    // uniform -> s_load
#pragma unroll
    for (int q = 0; q < 4; ++q) {
        const float4 nv = ((const float4*)nrow)[q];
        acc[q * 4 + 0] += brow[q * 4 + 0] + nv.x * 0.2f + 0.9f;
        acc[q * 4 + 1] += brow[q * 4 + 1] + nv.y * 0.2f + 0.9f;
        acc[q * 4 + 2] += brow[q * 4 + 2] + nv.z * 0.2f + 0.9f;
        acc[q * 4 + 3] += brow[q * 4 + 3] + nv.w * 0.2f + 0.9f;
    }

    // ---- local (group) max/argmax, then combine 4 groups via LDS ----
    float lm = acc[0]; int li = 0;
#pragma unroll
    for (int e = 1; e < EPG; ++e)
        if (acc[e] > lm) { lm = acc[e]; li = e; }   // strict > : first tie wins
    smax[lane][wv] = lm;
    sidx[lane][wv] = g16 + li;
    __syncthreads();

    float M = smax[lane][0]; int bi = sidx[lane][0];
#pragma unroll
    for (int g2 = 1; g2 < 4; ++g2) {
        const float m2 = smax[lane][g2];
        if (m2 > M) { M = m2; bi = sidx[lane][g2]; }  // ascending g2 + strict > = lowest idx on tie
    }

    float s = 0.f;
#pragma unroll
    for (int e = 0; e < EPG; ++e) { acc[e] = __expf(acc[e] - M); s += acc[e]; }
    ssum[lane][wv] = s;
    __syncthreads();
    const float denom = ssum[lane][0] + ssum[lane][1] + ssum[lane][2] + ssum[lane][3];
    const float inv = 1.0f / denom;
#pragma unroll
    for (int e = 0; e < EPG; ++e) acc[e] *= inv;

    if (wv == 0) out[NTOK + token] = inv;   // top1 prob = exp(0)/denom

    // ---- per-wave column sums: constant-bound butterfly (rule #20 safe) ----
#define XSTAGE(M_)                                                       \
    {                                                                    \
        const bool up_ = (lane & (M_)) != 0;                             \
        _Pragma("unroll")                                                \
        for (int j = 0; j < (M_); ++j) {                                 \
            const float a_ = acc[j], b_ = acc[j + (M_)];                 \
            const float r_ = __shfl_xor(up_ ? a_ : b_, (M_), 64);        \
            acc[j] = (up_ ? b_ : a_) + r_;                               \
        }                                                                \
    }
    XSTAGE(8) XSTAGE(4) XSTAGE(2) XSTAGE(1)
#undef XSTAGE
    float cs = acc[0];
    cs += __shfl_xor(cs, 16, 64);
    cs += __shfl_xor(cs, 32, 64);
    if (lane < EPG) colpart[blk * NE + g16 + lane] = cs;  // expert g16+lane column sum

    // ---- stable within-block rank + histogram: wave 0 only (lane == token) ----
    if (wv == 0) {
        const uint64_t below = (1ull << lane) - 1ull;
        int lrank = 0, h = 0;
#pragma unroll 1
        for (int e = 0; e < NE; ++e) {
            const uint64_t mb = __ballot(bi == e);
            if (bi == e)   lrank = (int)__popcll(mb & below);
            if (lane == e) h = (int)__popcll(mb);
        }
        pk[token] = bi | (lrank << 6);      // pack: 6b expert + local rank
        histg[blk * NE + lane] = h;
    }
}

// ---------------------------------------------------------------------------
// scan_kernel v2 (R5): 64 blocks, one per expert. Thread t owns 8 block-
// histogram entries; wave shfl_up prefix + cross-wave LDS offsets -> in-place
// exclusive scan of hist. Also emits per-expert total + softmax column sum.
// R4 post-mortem: old 1-block scan was 512 latency-serial global round-trips.
// ---------------------------------------------------------------------------
__global__ __launch_bounds__(256)
void scan_kernel(int* __restrict__ hist, const float* __restrict__ colpart,
                 int* __restrict__ totals, float* __restrict__ colsums)
{
    __shared__ int   wtot[4];
    __shared__ float wcs[4];
    const int e    = blockIdx.x;
    const int t    = threadIdx.x;
    const int lane = t & 63;
    const int w    = t >> 6;
    const int b0   = t * 8;

    int h[8]; int s = 0; float csl = 0.f;
#pragma unroll
    for (int i = 0; i < 8; ++i) {
        h[i]  = hist[(b0 + i) * NE + e];
        csl  += colpart[(b0 + i) * NE + e];
        s    += h[i];
    }
    // wave inclusive prefix over per-thread sums
    int inc = s;
#pragma unroll
    for (int d = 1; d < 64; d <<= 1) {
        const int v = __shfl_up(inc, d, 64);
        if (lane >= d) inc += v;
    }
    float wsum = csl;
#pragma unroll
    for (int m = 32; m; m >>= 1) wsum += __shfl_xor(wsum, m, 64);
    if (lane == 63) wtot[w] = inc;
    if (lane == 0)  wcs[w]  = wsum;
    __syncthreads();

    int base = 0;
#pragma unroll
    for (int ww = 0; ww < 4; ++ww) base += (ww < w) ? wtot[ww] : 0;
    int run = base + inc - s;   // exclusive prefix for this thread's first entry
#pragma unroll
    for (int i = 0; i < 8; ++i) { hist[(b0 + i) * NE + e] = run; run += h[i]; }

    if (t == 0) {
        totals[e]  = wtot[0] + wtot[1] + wtot[2] + wtot[3];
        colsums[e] = wcs[0] + wcs[1] + wcs[2] + wcs[3];
    }
}

// ---------------------------------------------------------------------------
// loss_kernel: 1 wave; loss = 64/nv^2 * sum_e min(total_e,CAP)*colsum_e
// ---------------------------------------------------------------------------
__global__ void loss_kernel(const int* __restrict__ totals,
                            const float* __restrict__ colsums,
                            float* __restrict__ out)
{
    const int e   = threadIdx.x;
    const int tot = totals[e];
    const float cnt = (float)((tot < CAP) ? tot : CAP);
    float nv = cnt, contrib = cnt * colsums[e];
#pragma unroll
    for (int m = 32; m; m >>= 1) {
        nv      += __shfl_xor(nv, m, 64);
        contrib += __shfl_xor(contrib, m, 64);
    }
    if (e == 0) out[2 * NTOK] = 64.0f * contrib / (nv * nv);
}

// ---------------------------------------------------------------------------
// finalize: global rank = local rank + block offset; write pruned idx as float.
// ---------------------------------------------------------------------------
__global__ void finalize_kernel(const int* __restrict__ pk, const int* __restrict__ offs,
                                float* __restrict__ out)
{
    const int i = blockIdx.x * 256 + threadIdx.x;
    const int v = pk[i];
    const int e = v & 63;
    const int r = (v >> 6) + offs[(i >> 6) * NE + e];
    out[i] = (r < CAP) ? (float)e : -1.0f;
}

extern "C" void kernel_launch(void* const* d_in, const int* in_sizes, int n_in,
                              void* d_out, int out_size, void* d_ws, size_t ws_size,
                              hipStream_t stream)
{
    (void)in_sizes; (void)n_in; (void)out_size; (void)ws_size;
    const float* A     = (const float*)d_in[0];
    const float* W     = (const float*)d_in[1];
    const float* bias  = (const float*)d_in[2];
    const float* noise = (const float*)d_in[3];
    float* out = (float*)d_out;

    char* ws = (char*)d_ws;
    int*   pkbuf   = (int*)ws;                       // 512 KB
    int*   histg   = (int*)(ws + 524288);            // 512 KB (becomes offsets in-place)
    float* colpart = (float*)(ws + 2 * 524288);      // 512 KB
    int*   totals  = (int*)(ws + 3 * 524288);        // 256 B
    float* colsums = (float*)(ws + 3 * 524288 + 256);// 256 B

    gate_kernel<<<NBLK, 256, 0, stream>>>(A, W, bias, noise, out, pkbuf, histg, colpart);
    scan_kernel<<<NE, 256, 0, stream>>>(histg, colpart, totals, colsums);
    loss_kernel<<<1, 64, 0, stream>>>(totals, colsums, out);
    finalize_kernel<<<NTOK / 256, 256, 0, stream>>>(pkbuf, histg, out);
}